// Round 2
// baseline (106.607 us; speedup 1.0000x reference)
//
#include <hip/hip_runtime.h>
#include <stdint.h>

#define N_ROWS 8192
#define N_DIM  256

typedef __attribute__((ext_vector_type(8))) short bf16x8;
typedef __attribute__((ext_vector_type(4))) float f32x4;

__device__ inline unsigned short f2bf(float f) {
    unsigned u = __float_as_uint(f);
    unsigned r = (u + 0x7FFFu + ((u >> 16) & 1u)) >> 16;
    return (unsigned short)r;
}
__device__ inline float bf2f(unsigned short b) {
    return __uint_as_float(((unsigned)b) << 16);
}
// order-preserving float->uint encoding (unsigned compare == float compare)
__device__ inline unsigned encf(float f) {
    unsigned u = __float_as_uint(f);
    return u ^ ((u & 0x80000000u) ? 0xFFFFFFFFu : 0x80000000u);
}
__device__ inline float decf(unsigned e) {
    unsigned u = e ^ ((e & 0x80000000u) ? 0x80000000u : 0xFFFFFFFFu);
    return __uint_as_float(u);
}
#define ENC_BIG 0xF149F2CAu  // encf(1e30f)

// K1: L2-normalize rows, convert to bf16, n_i = ||bf16(z_i)||^2, init rmin.
// One wave per row. In in-place mode zb/nsqb/rminb alias the x buffer: each
// lane's stores land only in bytes this wave already loaded into registers.
__global__ __launch_bounds__(256) void k_norm(const float* x,
                                              char* zb, long zstride,
                                              char* nsqb, long nstride,
                                              char* rminb, long rstride,
                                              float* out) {
    if (blockIdx.x == 0 && threadIdx.x == 0) *out = 0.0f;  // ordered before k_final
    const int lane = threadIdx.x & 63;
    const int w    = threadIdx.x >> 6;
    const int row  = blockIdx.x * 4 + w;
    const float4* xr = (const float4*)(x + (size_t)row * N_DIM);
    float4 v = xr[lane];
    float ss = v.x*v.x + v.y*v.y + v.z*v.z + v.w*v.w;
    #pragma unroll
    for (int m = 1; m < 64; m <<= 1) ss += __shfl_xor(ss, m, 64);
    const float inv = 1.0f / sqrtf(ss);
    unsigned short b0 = f2bf(v.x * inv);
    unsigned short b1 = f2bf(v.y * inv);
    unsigned short b2 = f2bf(v.z * inv);
    unsigned short b3 = f2bf(v.w * inv);
    ushort4 uv; uv.x = b0; uv.y = b1; uv.z = b2; uv.w = b3;
    *(ushort4*)(zb + (size_t)row * zstride + lane * 8) = uv;
    float z0 = bf2f(b0), z1 = bf2f(b1), z2 = bf2f(b2), z3 = bf2f(b3);
    float s2 = z0*z0 + z1*z1 + z2*z2 + z3*z3;
    #pragma unroll
    for (int m = 1; m < 64; m <<= 1) s2 += __shfl_xor(s2, m, 64);
    if (lane == 0) {
        *(float*)(nsqb + (size_t)row * nstride) = s2;
        *(unsigned*)(rminb + (size_t)row * rstride) = ENC_BIG;
    }
}

#define GLD_LDS16(g, l)                                                        \
    __builtin_amdgcn_global_load_lds(                                          \
        (const __attribute__((address_space(1))) unsigned int*)(g),            \
        (__attribute__((address_space(3))) unsigned int*)(l), 16, 0, 0)

// K2: S = Z * Z^T (bf16 MFMA, 128x128 tile), fused epilogue: per-row min over
// this block's 128 cols of (n_j - 2*s_ij), diag excluded; atomicMin to rmin.
__global__ __launch_bounds__(256) void k_gemm(const char* zb, long zstride,
                                              const char* nsqb, long nstride,
                                              char* rminb, long rstride) {
    __shared__ unsigned short As[128 * 32];   // 8 KB
    __shared__ unsigned short Bs[128 * 32];   // 8 KB
    __shared__ float pmin[128][2];

    const int tid   = threadIdx.x;
    const int lane  = tid & 63;
    const int w     = tid >> 6;
    const int waveM = (w >> 1) * 64;
    const int waveN = (w & 1) * 64;
    const int br    = blockIdx.x;
    const int bc    = blockIdx.y;

    const char* gA = zb + (size_t)br * 128 * zstride;
    const char* gB = zb + (size_t)bc * 128 * zstride;

    f32x4 acc[4][4];
    #pragma unroll
    for (int m = 0; m < 4; ++m)
        #pragma unroll
        for (int n = 0; n < 4; ++n)
            acc[m][n] = (f32x4){0.f, 0.f, 0.f, 0.f};

    for (int kk = 0; kk < N_DIM; kk += 32) {
        __syncthreads();
        #pragma unroll
        for (int c = 0; c < 2; ++c) {
            const int f   = c * 4096 + tid * 16;  // flat byte in 8 KB tile
            const int row = f >> 6;               // 64 B per tile-row (K-slice)
            const int cb  = f & 63;
            GLD_LDS16(gA + (size_t)row * zstride + kk * 2 + cb,
                      (char*)As + c * 4096 + w * 1024);
            GLD_LDS16(gB + (size_t)row * zstride + kk * 2 + cb,
                      (char*)Bs + c * 4096 + w * 1024);
        }
        __syncthreads();

        bf16x8 af[4], bfr[4];
        #pragma unroll
        for (int m = 0; m < 4; ++m)
            af[m] = *(const bf16x8*)&As[(waveM + m*16 + (lane & 15)) * 32 + (lane >> 4) * 8];
        #pragma unroll
        for (int n = 0; n < 4; ++n)
            bfr[n] = *(const bf16x8*)&Bs[(waveN + n*16 + (lane & 15)) * 32 + (lane >> 4) * 8];
        #pragma unroll
        for (int m = 0; m < 4; ++m)
            #pragma unroll
            for (int n = 0; n < 4; ++n)
                acc[m][n] = __builtin_amdgcn_mfma_f32_16x16x32_bf16(af[m], bfr[n], acc[m][n], 0, 0, 0);
    }

    // Epilogue. C layout: col = lane&15, row = (lane>>4)*4 + reg  [m89]
    float nj[4];
    #pragma unroll
    for (int n = 0; n < 4; ++n)
        nj[n] = *(const float*)(nsqb + (size_t)(bc * 128 + waveN + n * 16 + (lane & 15)) * nstride);

    float rmin[4][4];
    #pragma unroll
    for (int m = 0; m < 4; ++m)
        #pragma unroll
        for (int r = 0; r < 4; ++r)
            rmin[m][r] = 1e30f;

    const int grow0 = br * 128 + waveM + (lane >> 4) * 4;
    const int gcol0 = bc * 128 + waveN + (lane & 15);
    #pragma unroll
    for (int m = 0; m < 4; ++m) {
        #pragma unroll
        for (int n = 0; n < 4; ++n) {
            #pragma unroll
            for (int r = 0; r < 4; ++r) {
                float t = fmaf(-2.0f, acc[m][n][r], nj[n]);
                const bool diag = (grow0 + m * 16 + r) == (gcol0 + n * 16);
                t = diag ? 1e30f : t;
                rmin[m][r] = fminf(rmin[m][r], t);
            }
        }
    }
    #pragma unroll
    for (int mask = 1; mask < 16; mask <<= 1) {
        #pragma unroll
        for (int m = 0; m < 4; ++m)
            #pragma unroll
            for (int r = 0; r < 4; ++r)
                rmin[m][r] = fminf(rmin[m][r], __shfl_xor(rmin[m][r], mask, 64));
    }
    if ((lane & 15) == 0) {
        const int q = lane >> 4;
        #pragma unroll
        for (int m = 0; m < 4; ++m)
            #pragma unroll
            for (int r = 0; r < 4; ++r)
                pmin[waveM + m * 16 + q * 4 + r][w & 1] = rmin[m][r];
    }
    __syncthreads();
    if (tid < 128) {
        const float v = fminf(pmin[tid][0], pmin[tid][1]);
        atomicMin((unsigned*)(rminb + (size_t)(br * 128 + tid) * rstride), encf(v));
    }
}

// K3: res_i = n_i + rmin_i; loss = max(1/sqrt(max(res,1e-30)), 0.1); mean.
__global__ __launch_bounds__(256) void k_final(const char* nsqb, long nstride,
                                               const char* rminb, long rstride,
                                               float* out) {
    const int r = blockIdx.x * 256 + threadIdx.x;
    const float mn  = decf(*(const unsigned*)(rminb + (size_t)r * rstride));
    const float nsq = *(const float*)(nsqb + (size_t)r * nstride);
    const float res = fmaxf(nsq + mn, 1e-30f);
    float loss = fmaxf(1.0f / sqrtf(res), 0.1f);  // 0.1 == 1/(diag ~ 10)
    #pragma unroll
    for (int m = 1; m < 64; m <<= 1) loss += __shfl_xor(loss, m, 64);
    __shared__ float wsum[4];
    const int lane = threadIdx.x & 63, w = threadIdx.x >> 6;
    if (lane == 0) wsum[w] = loss;
    __syncthreads();
    if (threadIdx.x == 0)
        atomicAdd(out, (wsum[0] + wsum[1] + wsum[2] + wsum[3]) * (1.0f / 8192.0f));
}

extern "C" void kernel_launch(void* const* d_in, const int* in_sizes, int n_in,
                              void* d_out, int out_size, void* d_ws, size_t ws_size,
                              hipStream_t stream) {
    float* x   = (float*)d_in[0];
    float* out = (float*)d_out;
    char*  ws  = (char*)d_ws;

    // ws layout: zb 4 MB | nsq 32 KB | rmin 32 KB  (4.0625 MB + margin)
    const size_t WS_NEED = 4u * 1024 * 1024 + 64 * 1024 + 4096;
    char *zb, *nsqb, *rminb;
    long zstride, nstride, rstride;
    if (ws_size >= WS_NEED) {
        zb    = ws;                              zstride = 512;
        nsqb  = ws + 4u * 1024 * 1024;           nstride = 4;
        rminb = ws + 4u * 1024 * 1024 + 32*1024; rstride = 4;
    } else {
        // In-place inside x: bf16 row in first 512 B of each 1 KB row,
        // nsq @ +512, rmin @ +516. Harness restores d_in before every launch.
        zb    = (char*)x;       zstride = 1024;
        nsqb  = (char*)x + 512; nstride = 1024;
        rminb = (char*)x + 516; rstride = 1024;
    }

    k_norm<<<N_ROWS / 4, 256, 0, stream>>>(x, zb, zstride, nsqb, nstride, rminb, rstride, out);
    k_gemm<<<dim3(N_ROWS / 128, N_ROWS / 128), 256, 0, stream>>>(zb, zstride, nsqb, nstride, rminb, rstride);
    k_final<<<N_ROWS / 256, 256, 0, stream>>>(nsqb, nstride, rminb, rstride, out);
}

// Round 3
// 99.157 us; speedup vs baseline: 1.0751x; 1.0751x over previous
//
#include <hip/hip_runtime.h>
#include <stdint.h>

#define N_ROWS 8192
#define N_DIM  256
#define NB     64          // 8192 / 128 row-blocks
#define NTRI   2080        // NB*(NB+1)/2

typedef __attribute__((ext_vector_type(8))) short bf16x8;
typedef __attribute__((ext_vector_type(4))) float f32x4;

__device__ inline unsigned short f2bf(float f) {
    unsigned u = __float_as_uint(f);
    unsigned r = (u + 0x7FFFu + ((u >> 16) & 1u)) >> 16;
    return (unsigned short)r;
}
__device__ inline float bf2f(unsigned short b) {
    return __uint_as_float(((unsigned)b) << 16);
}
// order-preserving float->uint encoding (unsigned compare == float compare)
__device__ inline unsigned encf(float f) {
    unsigned u = __float_as_uint(f);
    return u ^ ((u & 0x80000000u) ? 0xFFFFFFFFu : 0x80000000u);
}
__device__ inline float decf(unsigned e) {
    unsigned u = e ^ ((e & 0x80000000u) ? 0x80000000u : 0xFFFFFFFFu);
    return __uint_as_float(u);
}
#define ENC_BIG 0xF149F2CAu  // encf(1e30f)

// K1: L2-normalize rows, convert to bf16, n_i = ||bf16(z_i)||^2, init rmin.
__global__ __launch_bounds__(256) void k_norm(const float* x,
                                              char* zb, long zstride,
                                              char* nsqb, long nstride,
                                              char* rminb, long rstride,
                                              float* out) {
    if (blockIdx.x == 0 && threadIdx.x == 0) *out = 0.0f;  // ordered before k_final
    const int lane = threadIdx.x & 63;
    const int w    = threadIdx.x >> 6;
    const int row  = blockIdx.x * 4 + w;
    const float4* xr = (const float4*)(x + (size_t)row * N_DIM);
    float4 v = xr[lane];
    float ss = v.x*v.x + v.y*v.y + v.z*v.z + v.w*v.w;
    #pragma unroll
    for (int m = 1; m < 64; m <<= 1) ss += __shfl_xor(ss, m, 64);
    const float inv = 1.0f / sqrtf(ss);
    unsigned short b0 = f2bf(v.x * inv);
    unsigned short b1 = f2bf(v.y * inv);
    unsigned short b2 = f2bf(v.z * inv);
    unsigned short b3 = f2bf(v.w * inv);
    ushort4 uv; uv.x = b0; uv.y = b1; uv.z = b2; uv.w = b3;
    *(ushort4*)(zb + (size_t)row * zstride + lane * 8) = uv;
    float z0 = bf2f(b0), z1 = bf2f(b1), z2 = bf2f(b2), z3 = bf2f(b3);
    float s2 = z0*z0 + z1*z1 + z2*z2 + z3*z3;
    #pragma unroll
    for (int m = 1; m < 64; m <<= 1) s2 += __shfl_xor(s2, m, 64);
    if (lane == 0) {
        *(float*)(nsqb + (size_t)row * nstride) = s2;
        *(unsigned*)(rminb + (size_t)row * rstride) = ENC_BIG;
    }
}

#define GLD_LDS16(g, l)                                                        \
    __builtin_amdgcn_global_load_lds(                                          \
        (const __attribute__((address_space(1))) unsigned int*)(g),            \
        (__attribute__((address_space(3))) unsigned int*)(l), 16, 0, 0)

// K2: upper-triangle 128x128 blocks of S = Z*Z^T (bf16 MFMA). Fused epilogue:
// per-row min AND per-col min of (n_j - 2*s_ij); atomicMin into rmin.
// LDS layout XOR-swizzled: chunk slot = c ^ ((row>>1)&3)  -> 2-way reads (free).
__global__ __launch_bounds__(256) void k_gemm(const char* zb, long zstride,
                                              const char* nsqb, long nstride,
                                              char* rminb, long rstride) {
    __shared__ unsigned short As[128 * 32];   // 8 KB
    __shared__ unsigned short Bs[128 * 32];   // 8 KB
    __shared__ float pminR[128][2];
    __shared__ float pminC[128][2];

    const int tid   = threadIdx.x;
    const int lane  = tid & 63;
    const int w     = tid >> 6;
    const int waveM = (w >> 1) * 64;
    const int waveN = (w & 1) * 64;

    // triangle decode: t -> (br, bc), br <= bc ; start(b) = b*(129-b)/2
    const int t = blockIdx.x;
    int br = (int)((129.0f - sqrtf(16641.0f - 8.0f * (float)t)) * 0.5f);
    while ((br + 1) * (129 - (br + 1)) / 2 <= t) ++br;
    while (br * (129 - br) / 2 > t) --br;
    const int bc = br + (t - br * (129 - br) / 2);
    const bool isdiag = (br == bc);

    const char* gA = zb + (size_t)br * 128 * zstride;
    const char* gB = zb + (size_t)bc * 128 * zstride;

    f32x4 acc[4][4];
    #pragma unroll
    for (int m = 0; m < 4; ++m)
        #pragma unroll
        for (int n = 0; n < 4; ++n)
            acc[m][n] = (f32x4){0.f, 0.f, 0.f, 0.f};

    for (int kk = 0; kk < N_DIM; kk += 32) {
        __syncthreads();
        #pragma unroll
        for (int c = 0; c < 2; ++c) {
            const int f    = c * 4096 + tid * 16;     // flat LDS byte this lane fills
            const int row  = f >> 6;                  // 64 B per tile-row
            const int c_st = (f >> 4) & 3;            // stored chunk slot
            const int c_g  = c_st ^ ((row >> 1) & 3); // source chunk (XOR swizzle)
            GLD_LDS16(gA + (size_t)row * zstride + kk * 2 + c_g * 16,
                      (char*)As + c * 4096 + w * 1024);
            GLD_LDS16(gB + (size_t)row * zstride + kk * 2 + c_g * 16,
                      (char*)Bs + c * 4096 + w * 1024);
        }
        __syncthreads();

        bf16x8 af[4], bfr[4];
        const int q = lane >> 4;  // k-chunk 0..3
        #pragma unroll
        for (int m = 0; m < 4; ++m) {
            const int rr = waveM + m * 16 + (lane & 15);
            af[m] = *(const bf16x8*)&As[rr * 32 + ((q ^ ((rr >> 1) & 3)) << 3)];
        }
        #pragma unroll
        for (int n = 0; n < 4; ++n) {
            const int rr = waveN + n * 16 + (lane & 15);
            bfr[n] = *(const bf16x8*)&Bs[rr * 32 + ((q ^ ((rr >> 1) & 3)) << 3)];
        }
        #pragma unroll
        for (int m = 0; m < 4; ++m)
            #pragma unroll
            for (int n = 0; n < 4; ++n)
                acc[m][n] = __builtin_amdgcn_mfma_f32_16x16x32_bf16(af[m], bfr[n], acc[m][n], 0, 0, 0);
    }

    // ---- epilogue. C layout: col = lane&15, row = (lane>>4)*4 + reg  [m89]
    float nj[4], ni[4];
    #pragma unroll
    for (int n = 0; n < 4; ++n)
        nj[n] = *(const float*)(nsqb + (size_t)(bc * 128 + waveN + n * 16 + (lane & 15)) * nstride);
    #pragma unroll
    for (int m = 0; m < 4; ++m)
        ni[m] = *(const float*)(nsqb + (size_t)(br * 128 + waveM + m * 16 + (lane >> 4) * 4) * nstride);
    // note: ni loaded per reg below instead (row varies with r) — recompute cheaply:
    // we only need n_i for the col-min path: t_col = n_i - 2 s_ij (then add n_j in k_final).

    float rminv[4][4];   // per (m, reg): row-direction min of (n_j - 2 s)
    float cminv[4];      // per n: col-direction min of (n_i - 2 s)
    #pragma unroll
    for (int m = 0; m < 4; ++m)
        #pragma unroll
        for (int r = 0; r < 4; ++r)
            rminv[m][r] = 1e30f;
    #pragma unroll
    for (int n = 0; n < 4; ++n)
        cminv[n] = 1e30f;

    const int lrow0 = waveM + (lane >> 4) * 4;  // local row base
    const int lcol0 = waveN + (lane & 15);      // local col
    #pragma unroll
    for (int m = 0; m < 4; ++m) {
        #pragma unroll
        for (int r = 0; r < 4; ++r) {
            const int lr = lrow0 + m * 16 + r;
            const float nir = *(const float*)(nsqb + (size_t)(br * 128 + lr) * nstride);
            #pragma unroll
            for (int n = 0; n < 4; ++n) {
                const float s = acc[m][n][r];
                const bool diag = isdiag && (lr == (lcol0 + n * 16));
                float tr = fmaf(-2.0f, s, nj[n]);        // n_j - 2s  (row path)
                tr = diag ? 1e30f : tr;
                rminv[m][r] = fminf(rminv[m][r], tr);
                if (!isdiag) {
                    const float tc = fmaf(-2.0f, s, nir); // n_i - 2s  (col path)
                    cminv[n] = fminf(cminv[n], tc);
                }
            }
        }
    }
    // row-min: reduce across the 16 lanes sharing a row (bits 0..3 of lane)
    #pragma unroll
    for (int mask = 1; mask < 16; mask <<= 1)
        #pragma unroll
        for (int m = 0; m < 4; ++m)
            #pragma unroll
            for (int r = 0; r < 4; ++r)
                rminv[m][r] = fminf(rminv[m][r], __shfl_xor(rminv[m][r], mask, 64));
    if ((lane & 15) == 0) {
        const int q = lane >> 4;
        #pragma unroll
        for (int m = 0; m < 4; ++m)
            #pragma unroll
            for (int r = 0; r < 4; ++r)
                pminR[waveM + m * 16 + q * 4 + r][w & 1] = rminv[m][r];
    }
    if (!isdiag) {
        // col-min: reduce across the 4 quads (bits 4..5 of lane)
        #pragma unroll
        for (int mask = 16; mask < 64; mask <<= 1)
            #pragma unroll
            for (int n = 0; n < 4; ++n)
                cminv[n] = fminf(cminv[n], __shfl_xor(cminv[n], mask, 64));
        if (lane < 16) {
            #pragma unroll
            for (int n = 0; n < 4; ++n)
                pminC[waveN + n * 16 + lane][w >> 1] = cminv[n];
        }
    }
    __syncthreads();
    if (tid < 128) {
        const float v = fminf(pminR[tid][0], pminR[tid][1]);
        atomicMin((unsigned*)(rminb + (size_t)(br * 128 + tid) * rstride), encf(v));
        if (!isdiag) {
            const float vc = fminf(pminC[tid][0], pminC[tid][1]);
            atomicMin((unsigned*)(rminb + (size_t)(bc * 128 + tid) * rstride), encf(vc));
        }
    }
}

// K3: res_i = n_i + rmin_i; loss = max(1/sqrt(max(res,1e-30)), 0.1); mean.
__global__ __launch_bounds__(256) void k_final(const char* nsqb, long nstride,
                                               const char* rminb, long rstride,
                                               float* out) {
    const int r = blockIdx.x * 256 + threadIdx.x;
    const float mn  = decf(*(const unsigned*)(rminb + (size_t)r * rstride));
    const float nsq = *(const float*)(nsqb + (size_t)r * nstride);
    const float res = fmaxf(nsq + mn, 1e-30f);
    float loss = fmaxf(1.0f / sqrtf(res), 0.1f);  // 0.1 == 1/(diag ~ 10)
    #pragma unroll
    for (int m = 1; m < 64; m <<= 1) loss += __shfl_xor(loss, m, 64);
    __shared__ float wsum[4];
    const int lane = threadIdx.x & 63, w = threadIdx.x >> 6;
    if (lane == 0) wsum[w] = loss;
    __syncthreads();
    if (threadIdx.x == 0)
        atomicAdd(out, (wsum[0] + wsum[1] + wsum[2] + wsum[3]) * (1.0f / 8192.0f));
}

extern "C" void kernel_launch(void* const* d_in, const int* in_sizes, int n_in,
                              void* d_out, int out_size, void* d_ws, size_t ws_size,
                              hipStream_t stream) {
    float* x   = (float*)d_in[0];
    float* out = (float*)d_out;
    char*  ws  = (char*)d_ws;

    // ws layout: zb 4 MB | nsq 32 KB | rmin 32 KB
    const size_t WS_NEED = 4u * 1024 * 1024 + 64 * 1024 + 4096;
    char *zb, *nsqb, *rminb;
    long zstride, nstride, rstride;
    if (ws_size >= WS_NEED) {
        zb    = ws;                                zstride = 512;
        nsqb  = ws + 4u * 1024 * 1024;             nstride = 4;
        rminb = ws + 4u * 1024 * 1024 + 32 * 1024; rstride = 4;
    } else {
        // In-place inside x (harness restores d_in before every launch):
        // bf16 row in first 512 B of each 1 KB row, nsq @ +512, rmin @ +516.
        zb    = (char*)x;       zstride = 1024;
        nsqb  = (char*)x + 512; nstride = 1024;
        rminb = (char*)x + 516; rstride = 1024;
    }

    k_norm<<<N_ROWS / 4, 256, 0, stream>>>(x, zb, zstride, nsqb, nstride, rminb, rstride, out);
    k_gemm<<<NTRI, 256, 0, stream>>>(zb, zstride, nsqb, nstride, rminb, rstride);
    k_final<<<N_ROWS / 256, 256, 0, stream>>>(nsqb, nstride, rminb, rstride, out);
}

// Round 4
// 89.956 us; speedup vs baseline: 1.1851x; 1.1023x over previous
//
#include <hip/hip_runtime.h>
#include <stdint.h>

#define N_ROWS 8192
#define N_DIM  256
#define NB     64          // 8192 / 128 row-blocks
#define NTRI   2080        // NB*(NB+1)/2

typedef __attribute__((ext_vector_type(8))) short bf16x8;
typedef __attribute__((ext_vector_type(4))) float f32x4;

__device__ inline unsigned short f2bf(float f) {
    unsigned u = __float_as_uint(f);
    unsigned r = (u + 0x7FFFu + ((u >> 16) & 1u)) >> 16;
    return (unsigned short)r;
}
__device__ inline float bf2f(unsigned short b) {
    return __uint_as_float(((unsigned)b) << 16);
}
// order-preserving float->uint encoding (unsigned compare == float compare)
__device__ inline unsigned encf(float f) {
    unsigned u = __float_as_uint(f);
    return u ^ ((u & 0x80000000u) ? 0xFFFFFFFFu : 0x80000000u);
}
__device__ inline float decf(unsigned e) {
    unsigned u = e ^ ((e & 0x80000000u) ? 0x80000000u : 0xFFFFFFFFu);
    return __uint_as_float(u);
}
#define ENC_BIG 0xF149F2CAu  // encf(1e30f)

// K1: L2-normalize rows, convert to bf16, n_i = ||bf16(z_i)||^2, init rmin.
__global__ __launch_bounds__(256) void k_norm(const float* x,
                                              char* zb, long zstride,
                                              char* nsqb, long nstride,
                                              char* rminb, long rstride,
                                              float* out) {
    if (blockIdx.x == 0 && threadIdx.x == 0) *out = 0.0f;  // ordered before k_final
    const int lane = threadIdx.x & 63;
    const int w    = threadIdx.x >> 6;
    const int row  = blockIdx.x * 4 + w;
    const float4* xr = (const float4*)(x + (size_t)row * N_DIM);
    float4 v = xr[lane];
    float ss = v.x*v.x + v.y*v.y + v.z*v.z + v.w*v.w;
    #pragma unroll
    for (int m = 1; m < 64; m <<= 1) ss += __shfl_xor(ss, m, 64);
    const float inv = 1.0f / sqrtf(ss);
    unsigned short b0 = f2bf(v.x * inv);
    unsigned short b1 = f2bf(v.y * inv);
    unsigned short b2 = f2bf(v.z * inv);
    unsigned short b3 = f2bf(v.w * inv);
    ushort4 uv; uv.x = b0; uv.y = b1; uv.z = b2; uv.w = b3;
    *(ushort4*)(zb + (size_t)row * zstride + lane * 8) = uv;
    float z0 = bf2f(b0), z1 = bf2f(b1), z2 = bf2f(b2), z3 = bf2f(b3);
    float s2 = z0*z0 + z1*z1 + z2*z2 + z3*z3;
    #pragma unroll
    for (int m = 1; m < 64; m <<= 1) s2 += __shfl_xor(s2, m, 64);
    if (lane == 0) {
        *(float*)(nsqb + (size_t)row * nstride) = s2;
        *(unsigned*)(rminb + (size_t)row * rstride) = ENC_BIG;
    }
}

#define GLD_LDS16(g, l)                                                        \
    __builtin_amdgcn_global_load_lds(                                          \
        (const __attribute__((address_space(1))) unsigned int*)(g),            \
        (__attribute__((address_space(3))) unsigned int*)(l), 16, 0, 0)

// K2: upper-triangle 128x128 blocks of S = Z*Z^T (bf16 MFMA). Fused epilogue:
// u_ij = n_i + n_j - 2 s_ij; per-row AND per-col min of u; atomicMin into rmin.
// LDS XOR-swizzled: chunk slot = c ^ ((row>>1)&3) -> conflict-free reads.
// __launch_bounds__(256,4): pin 4 waves/SIMD (128-reg unified budget).
__global__ __launch_bounds__(256, 4) void k_gemm(const char* zb, long zstride,
                                                 const char* nsqb, long nstride,
                                                 char* rminb, long rstride) {
    __shared__ unsigned short As[128 * 32];   // 8 KB
    __shared__ unsigned short Bs[128 * 32];   // 8 KB
    __shared__ float pminR[128][2];
    __shared__ float pminC[128][2];

    const int tid   = threadIdx.x;
    const int lane  = tid & 63;
    const int w     = tid >> 6;
    const int waveM = (w >> 1) * 64;
    const int waveN = (w & 1) * 64;

    // triangle decode: t -> (br, bc), br <= bc ; start(b) = b*(129-b)/2
    const int t = blockIdx.x;
    int br = (int)((129.0f - sqrtf(16641.0f - 8.0f * (float)t)) * 0.5f);
    while ((br + 1) * (129 - (br + 1)) / 2 <= t) ++br;
    while (br * (129 - br) / 2 > t) --br;
    const int bc = br + (t - br * (129 - br) / 2);
    const bool isdiag = (br == bc);

    const char* gA = zb + (size_t)br * 128 * zstride;
    const char* gB = zb + (size_t)bc * 128 * zstride;

    f32x4 acc[4][4];
    #pragma unroll
    for (int m = 0; m < 4; ++m)
        #pragma unroll
        for (int n = 0; n < 4; ++n)
            acc[m][n] = (f32x4){0.f, 0.f, 0.f, 0.f};

    for (int kk = 0; kk < N_DIM; kk += 32) {
        __syncthreads();
        #pragma unroll
        for (int c = 0; c < 2; ++c) {
            const int f    = c * 4096 + tid * 16;     // flat LDS byte this lane fills
            const int row  = f >> 6;                  // 64 B per tile-row
            const int c_st = (f >> 4) & 3;            // stored chunk slot
            const int c_g  = c_st ^ ((row >> 1) & 3); // source chunk (XOR swizzle)
            GLD_LDS16(gA + (size_t)row * zstride + kk * 2 + c_g * 16,
                      (char*)As + c * 4096 + w * 1024);
            GLD_LDS16(gB + (size_t)row * zstride + kk * 2 + c_g * 16,
                      (char*)Bs + c * 4096 + w * 1024);
        }
        __syncthreads();

        bf16x8 af[4], bfr[4];
        const int q = lane >> 4;  // k-chunk 0..3
        #pragma unroll
        for (int m = 0; m < 4; ++m) {
            const int rr = waveM + m * 16 + (lane & 15);
            af[m] = *(const bf16x8*)&As[rr * 32 + ((q ^ ((rr >> 1) & 3)) << 3)];
        }
        #pragma unroll
        for (int n = 0; n < 4; ++n) {
            const int rr = waveN + n * 16 + (lane & 15);
            bfr[n] = *(const bf16x8*)&Bs[rr * 32 + ((q ^ ((rr >> 1) & 3)) << 3)];
        }
        #pragma unroll
        for (int m = 0; m < 4; ++m)
            #pragma unroll
            for (int n = 0; n < 4; ++n)
                acc[m][n] = __builtin_amdgcn_mfma_f32_16x16x32_bf16(af[m], bfr[n], acc[m][n], 0, 0, 0);
    }

    // keep epilogue loads from being hoisted across the K-loop (VGPR pressure)
    asm volatile("" ::: "memory");

    // ---- epilogue. C layout: col = lane&15, row = (lane>>4)*4 + reg  [m89]
    float nj[4];
    #pragma unroll
    for (int n = 0; n < 4; ++n)
        nj[n] = *(const float*)(nsqb + (size_t)(bc * 128 + waveN + n * 16 + (lane & 15)) * nstride);

    float4 ni4[4];  // n_i for this lane's 16 rows; rows r..r+3 contiguous
    #pragma unroll
    for (int m = 0; m < 4; ++m) {
        const int row0 = br * 128 + waveM + m * 16 + (lane >> 4) * 4;
        if (nstride == 4) {
            ni4[m] = *(const float4*)(nsqb + (size_t)row0 * 4);
        } else {
            ni4[m].x = *(const float*)(nsqb + (size_t)(row0 + 0) * nstride);
            ni4[m].y = *(const float*)(nsqb + (size_t)(row0 + 1) * nstride);
            ni4[m].z = *(const float*)(nsqb + (size_t)(row0 + 2) * nstride);
            ni4[m].w = *(const float*)(nsqb + (size_t)(row0 + 3) * nstride);
        }
    }

    float rminv[4][4];   // per (m, reg): row-direction min of u
    float cminv[4];      // per n: col-direction min of u
    #pragma unroll
    for (int m = 0; m < 4; ++m)
        #pragma unroll
        for (int r = 0; r < 4; ++r)
            rminv[m][r] = 1e30f;
    #pragma unroll
    for (int n = 0; n < 4; ++n)
        cminv[n] = 1e30f;

    const int lrow0 = waveM + (lane >> 4) * 4;
    const int lcol0 = waveN + (lane & 15);
    #pragma unroll
    for (int m = 0; m < 4; ++m) {
        #pragma unroll
        for (int r = 0; r < 4; ++r) {
            const int lr = lrow0 + m * 16 + r;
            const float nir = ((const float*)&ni4[m])[r];
            #pragma unroll
            for (int n = 0; n < 4; ++n) {
                float u = fmaf(-2.0f, acc[m][n][r], nir + nj[n]);
                const bool diag = isdiag && (lr == (lcol0 + n * 16));
                u = diag ? 1e30f : u;
                rminv[m][r] = fminf(rminv[m][r], u);
                cminv[n]    = fminf(cminv[n], u);
            }
        }
    }
    // row-min: reduce across the 16 lanes sharing a row (lane bits 0..3)
    #pragma unroll
    for (int mask = 1; mask < 16; mask <<= 1)
        #pragma unroll
        for (int m = 0; m < 4; ++m)
            #pragma unroll
            for (int r = 0; r < 4; ++r)
                rminv[m][r] = fminf(rminv[m][r], __shfl_xor(rminv[m][r], mask, 64));
    if ((lane & 15) == 0) {
        const int q = lane >> 4;
        #pragma unroll
        for (int m = 0; m < 4; ++m)
            #pragma unroll
            for (int r = 0; r < 4; ++r)
                pminR[waveM + m * 16 + q * 4 + r][w & 1] = rminv[m][r];
    }
    if (!isdiag) {
        // col-min: reduce across the 4 quads (lane bits 4..5)
        #pragma unroll
        for (int mask = 16; mask < 64; mask <<= 1)
            #pragma unroll
            for (int n = 0; n < 4; ++n)
                cminv[n] = fminf(cminv[n], __shfl_xor(cminv[n], mask, 64));
        if (lane < 16) {
            #pragma unroll
            for (int n = 0; n < 4; ++n)
                pminC[waveN + n * 16 + lane][w >> 1] = cminv[n];
        }
    }
    __syncthreads();
    if (tid < 128) {
        const float v = fminf(pminR[tid][0], pminR[tid][1]);
        atomicMin((unsigned*)(rminb + (size_t)(br * 128 + tid) * rstride), encf(v));
        if (!isdiag) {
            const float vc = fminf(pminC[tid][0], pminC[tid][1]);
            atomicMin((unsigned*)(rminb + (size_t)(bc * 128 + tid) * rstride), encf(vc));
        }
    }
}

// K3: res_i = rmin_i (already full n_i+n_j-2s); loss = max(1/sqrt(max(res,1e-30)), 0.1); mean.
__global__ __launch_bounds__(256) void k_final(const char* nsqb, long nstride,
                                               const char* rminb, long rstride,
                                               float* out) {
    const int r = blockIdx.x * 256 + threadIdx.x;
    const float mn  = decf(*(const unsigned*)(rminb + (size_t)r * rstride));
    const float res = fmaxf(mn, 1e-30f);
    float loss = fmaxf(1.0f / sqrtf(res), 0.1f);  // 0.1 == 1/(diag ~ 10)
    #pragma unroll
    for (int m = 1; m < 64; m <<= 1) loss += __shfl_xor(loss, m, 64);
    __shared__ float wsum[4];
    const int lane = threadIdx.x & 63, w = threadIdx.x >> 6;
    if (lane == 0) wsum[w] = loss;
    __syncthreads();
    if (threadIdx.x == 0)
        atomicAdd(out, (wsum[0] + wsum[1] + wsum[2] + wsum[3]) * (1.0f / 8192.0f));
}

extern "C" void kernel_launch(void* const* d_in, const int* in_sizes, int n_in,
                              void* d_out, int out_size, void* d_ws, size_t ws_size,
                              hipStream_t stream) {
    float* x   = (float*)d_in[0];
    float* out = (float*)d_out;
    char*  ws  = (char*)d_ws;

    // ws layout: zb 4 MB | nsq 32 KB | rmin 32 KB
    const size_t WS_NEED = 4u * 1024 * 1024 + 64 * 1024 + 4096;
    char *zb, *nsqb, *rminb;
    long zstride, nstride, rstride;
    if (ws_size >= WS_NEED) {
        zb    = ws;                                zstride = 512;
        nsqb  = ws + 4u * 1024 * 1024;             nstride = 4;
        rminb = ws + 4u * 1024 * 1024 + 32 * 1024; rstride = 4;
    } else {
        // In-place inside x (harness restores d_in before every launch):
        // bf16 row in first 512 B of each 1 KB row, nsq @ +512, rmin @ +516.
        zb    = (char*)x;       zstride = 1024;
        nsqb  = (char*)x + 512; nstride = 1024;
        rminb = (char*)x + 516; rstride = 1024;
    }

    k_norm<<<N_ROWS / 4, 256, 0, stream>>>(x, zb, zstride, nsqb, nstride, rminb, rstride, out);
    k_gemm<<<NTRI, 256, 0, stream>>>(zb, zstride, nsqb, nstride, rminb, rstride);
    k_final<<<N_ROWS / 256, 256, 0, stream>>>(nsqb, nstride, rminb, rstride, out);
}